// Round 1
// baseline (821.611 us; speedup 1.0000x reference)
//
#include <hip/hip_runtime.h>
#include <cstddef>
#include <cstdint>

// GMM E-step: N=200000, K=16, D=64, fp32 in/out.
// R7: precompute rewritten as single-wave, register-resident, fully-unrolled
// Cholesky + triangular inverse (was 83us = 37% of total at 0.59% VALUBusy:
// 256 multi-wave barriers + LDS round-trips on the serial critical path).
// One wave per component; lane r owns row r of Sigma in VGPRs; all cross-lane
// traffic is compile-time-lane __shfl (v_readlane); zero barriers in the
// factorization. Estep (MFMA f16 hi/lo, verified R5) unchanged.

#define GMM_D 64
#define GMM_K 16

typedef _Float16 half8 __attribute__((ext_vector_type(8)));
typedef float f32x4 __attribute__((ext_vector_type(4)));

// ws: WA [16 comps][16 frags][64 lanes][8 f16] = 262144 B, then tv, cc (f32)
#define WA_BYTES (GMM_K * 16 * 64 * 8 * 2)

__device__ __forceinline__ float fast_rsqrt(float x) {
#if __has_builtin(__builtin_amdgcn_rsqf)
    // v_rsq_f32 (~1 ulp) + one Newton step -> full fp32 accuracy
    const float r = __builtin_amdgcn_rsqf(x);
    return r * (1.5f - 0.5f * x * r * r);
#else
    return 1.0f / sqrtf(x);
#endif
}

// ---------------------------------------------------------------------------
// Precompute: one WAVE (64 threads) per component, wave-synchronous.
// Lane r = row r (Cholesky) / column r (inverse). Both triangular loops are
// fully unrolled so every per-lane array index is a compile-time constant
// (runtime-indexed register arrays would spill to scratch).
// ---------------------------------------------------------------------------
__global__ __launch_bounds__(64) void gmm_precompute_kernel(
    const float* __restrict__ pi, const float* __restrict__ mus,
    const float* __restrict__ covs, _Float16* __restrict__ WA,
    float* __restrict__ tv, float* __restrict__ cc)
{
    const int k = blockIdx.x;
    const int r = threadIdx.x;  // lane id

    __shared__ float Wv[GMM_D][GMM_D + 1];  // W = L^{-1}, for t/swizzle epilogue

    // ---- load row r of Sigma into registers (16x float4, L2-resident) ----
    float A_r[GMM_D];
    {
        const float4* src = reinterpret_cast<const float4*>(
            covs + (size_t)k * GMM_D * GMM_D + (size_t)r * GMM_D);
        #pragma unroll
        for (int u = 0; u < GMM_D / 4; ++u) {
            const float4 v = src[u];
            A_r[4 * u + 0] = v.x; A_r[4 * u + 1] = v.y;
            A_r[4 * u + 2] = v.z; A_r[4 * u + 3] = v.w;
        }
    }

    // ---- register Cholesky, right-looking, zero barriers ----
    // After step j: A_r[j] = L[r][j] (valid for r >= j; lanes r < j hold junk
    // in cols > r that is never read: every broadcast reads lanes >= j).
    float mydiag = 1.0f, myrs = 1.0f;
    #pragma unroll
    for (int j = 0; j < GMM_D; ++j) {
        const float pivot = __shfl(A_r[j], j);       // lane j: valid diag
        const float rs = fast_rsqrt(pivot);
        const float valj = A_r[j] * rs;              // L[r][j]; lane j: sqrt(pivot)
        if (r == j) { mydiag = valj; myrs = rs; }
        A_r[j] = valj;
        #pragma unroll
        for (int p = j + 1; p < GMM_D; ++p)          // rank-1 trailing update
            A_r[p] -= valj * __shfl(valj, p);
    }

    // ---- inverse: lane r solves L w = e_r  (column r of W = L^{-1}) ----
    // w[i] == 0 for i < r propagates exactly -> no predication needed.
    // 4-way split accumulators break the serial FMA chain.
    float w[GMM_D];
    #pragma unroll
    for (int i = 0; i < GMM_D; ++i) {
        float a0 = (r == i) ? 1.0f : 0.0f, a1 = 0.0f, a2 = 0.0f, a3 = 0.0f;
        #pragma unroll
        for (int p = 0; p < i; ++p) {
            const float lip = __shfl(A_r[p], i);     // L[i][p], lane i valid
            const float tt = lip * w[p];
            if      ((p & 3) == 0) a0 -= tt;
            else if ((p & 3) == 1) a1 -= tt;
            else if ((p & 3) == 2) a2 -= tt;
            else                   a3 -= tt;
        }
        w[i] = ((a0 + a1) + (a2 + a3)) * __shfl(myrs, i);  // * 1/L[i][i]
    }

    // ---- dump W to LDS (lane r holds column r -> write transposed) ----
    #pragma unroll
    for (int i = 0; i < GMM_D; ++i)
        Wv[i][r] = w[i];          // consecutive addresses per instr: conflict-free
    __syncthreads();              // single wave: compiles to a waitcnt

    // ---- t = W mu (lane r computes row r; mk[] loads are wave-uniform) ----
    {
        const float* mk = mus + k * GMM_D;
        float s0 = 0.f, s1 = 0.f, s2 = 0.f, s3 = 0.f;
        #pragma unroll
        for (int c = 0; c < GMM_D; c += 4) {
            s0 += Wv[r][c + 0] * mk[c + 0];
            s1 += Wv[r][c + 1] * mk[c + 1];
            s2 += Wv[r][c + 2] * mk[c + 2];
            s3 += Wv[r][c + 3] * mk[c + 3];
        }
        tv[k * GMM_D + r] = (s0 + s1) + (s2 + s3);
    }

    // ---- swizzle W -> f16 hi/lo A-fragments (layout identical to R6) ----
    // frag f = mt*4+s: lane L elem u = W[mt*16 + (L&15)][(s&1)*32 + (L>>4)*8 + u],
    // s in {0,1}: hi ; {2,3}: lo. 16B/lane stores, coalesced.
    {
        const int lr = r & 15, q = r >> 4;
        #pragma unroll
        for (int f = 0; f < 16; ++f) {
            const int mt = f >> 2, s = f & 3;
            const int row = mt * 16 + lr;
            const int db = (s & 1) * 32 + q * 8;
            half8 hv;
            #pragma unroll
            for (int u = 0; u < 8; ++u) {
                const float v = Wv[row][db + u];
                _Float16 h = (_Float16)v;
                if (s >= 2) h = (_Float16)(v - (float)h);
                hv[u] = h;
            }
            *(half8*)(WA + ((size_t)((k * 16 + f) * 64) + r) * 8) = hv;
        }
    }

    // ---- c_k = log pi_k - sum(log L_ii) - 0.5*D*log(2*pi) ----
    {
        float ll = logf(mydiag);
        #pragma unroll
        for (int off = 32; off > 0; off >>= 1) ll += __shfl_down(ll, off);
        if (r == 0)
            cc[k] = logf(pi[k]) - ll - 0.5f * 64.0f * 1.8378770664093453f;
    }
}

// ---------------------------------------------------------------------------
// E-step (R5-verified, unchanged): block = 4 waves, 64 points; wave w owns
// comps 4w..4w+3. Per (comp, ntile): 4 Mtiles x 6 MFMA 16x16x32 f16 (hi*hi +
// hi*lo + lo*hi), C preloaded with -t, maha reduced in-register + 2 shfl_xor.
// ---------------------------------------------------------------------------
__global__ __launch_bounds__(256) void gmm_estep_kernel(
    const float* __restrict__ X, const _Float16* __restrict__ WA,
    const float* __restrict__ tv, const float* __restrict__ cc,
    float* __restrict__ out, int N)
{
    // xs row (per point): [hi 0..63 | lo 0..63 | pad 8] f16 = 136 (272 B)
    __shared__ _Float16 xs[64 * 136];
    __shared__ float lg[64 * 17];

    const int tid = threadIdx.x;

    // ---- stage X -> f16 hi/lo in LDS: thread t: point t/4, dims (t%4)*16.. ----
    {
        const int p = tid >> 2, qq = tid & 3;
        const int np = blockIdx.x * 64 + p;
        if (np < N) {
            const float4* src = reinterpret_cast<const float4*>(X + (size_t)np * GMM_D) + qq * 4;
            float vv[16];
            #pragma unroll
            for (int u = 0; u < 4; ++u) {
                const float4 v = src[u];
                vv[4 * u + 0] = v.x; vv[4 * u + 1] = v.y;
                vv[4 * u + 2] = v.z; vv[4 * u + 3] = v.w;
            }
            half8 h0, h1, l0, l1;
            #pragma unroll
            for (int u = 0; u < 8; ++u) {
                const _Float16 a = (_Float16)vv[u];
                const _Float16 b = (_Float16)vv[u + 8];
                h0[u] = a; l0[u] = (_Float16)(vv[u] - (float)a);
                h1[u] = b; l1[u] = (_Float16)(vv[u + 8] - (float)b);
            }
            _Float16* row = xs + p * 136;
            *(half8*)(row + qq * 16)          = h0;
            *(half8*)(row + qq * 16 + 8)      = h1;
            *(half8*)(row + 64 + qq * 16)     = l0;
            *(half8*)(row + 64 + qq * 16 + 8) = l1;
        }
    }
    __syncthreads();

    const int lane = tid & 63;
    const int wave = __builtin_amdgcn_readfirstlane(tid >> 6);
    const int pt = lane & 15;
    const int q  = lane >> 4;

    #pragma unroll 1
    for (int kk = 0; kk < 4; ++kk) {
        const int k = wave * 4 + kk;  // wave-uniform

        // A fragments: 16 x global_load_dwordx4, coalesced, L2-resident.
        half8 af[4][4];
        const _Float16* wab = WA + (size_t)k * 8192 + lane * 8;
        #pragma unroll
        for (int mt = 0; mt < 4; ++mt)
            #pragma unroll
            for (int s = 0; s < 4; ++s)
                af[mt][s] = *(const half8*)(wab + (mt * 4 + s) * 512);

        // nt-invariant accumulator inits: -t rows for each Mtile
        f32x4 tk4[4];
        #pragma unroll
        for (int mt = 0; mt < 4; ++mt)
            tk4[mt] = *(const f32x4*)(tv + k * 64 + mt * 16 + q * 4);

        #pragma unroll 1
        for (int nt = 0; nt < 4; ++nt) {
            const _Float16* xrow = xs + (nt * 16 + pt) * 136 + q * 8;
            const half8 bh0 = *(const half8*)(xrow);        // hi dims 0..31
            const half8 bh1 = *(const half8*)(xrow + 32);   // hi dims 32..63
            const half8 bl0 = *(const half8*)(xrow + 64);   // lo dims 0..31
            const half8 bl1 = *(const half8*)(xrow + 96);   // lo dims 32..63

            float mahaP = 0.0f;
            #pragma unroll
            for (int mt = 0; mt < 4; ++mt) {
                f32x4 c = -tk4[mt];
                c = __builtin_amdgcn_mfma_f32_16x16x32_f16(af[mt][0], bh0, c, 0, 0, 0);
                c = __builtin_amdgcn_mfma_f32_16x16x32_f16(af[mt][1], bh1, c, 0, 0, 0);
                c = __builtin_amdgcn_mfma_f32_16x16x32_f16(af[mt][0], bl0, c, 0, 0, 0);
                c = __builtin_amdgcn_mfma_f32_16x16x32_f16(af[mt][1], bl1, c, 0, 0, 0);
                c = __builtin_amdgcn_mfma_f32_16x16x32_f16(af[mt][2], bh0, c, 0, 0, 0);
                c = __builtin_amdgcn_mfma_f32_16x16x32_f16(af[mt][3], bh1, c, 0, 0, 0);
                mahaP += c[0] * c[0] + c[1] * c[1] + c[2] * c[2] + c[3] * c[3];
            }
            mahaP += __shfl_xor(mahaP, 16);
            mahaP += __shfl_xor(mahaP, 32);
            if (q == 0 && (blockIdx.x * 64 + nt * 16 + pt) < N)
                lg[(nt * 16 + pt) * 17 + k] = cc[k] - 0.5f * mahaP;
        }
    }
    __syncthreads();

    // softmax: 4 threads/point, one float4 each (contiguous stores)
    {
        const int p = tid >> 2, qq = tid & 3;
        const int np = blockIdx.x * 64 + p;
        if (np < N) {
            const float* row = &lg[p * 17];
            float m = row[0];
            #pragma unroll
            for (int j = 1; j < GMM_K; ++j) m = fmaxf(m, row[j]);
            float e[GMM_K];
            float s = 0.0f;
            #pragma unroll
            for (int j = 0; j < GMM_K; ++j) { e[j] = __expf(row[j] - m); s += e[j]; }
            const float inv = 1.0f / s;
            float4 v;
            v.x = e[qq * 4 + 0] * inv;
            v.y = e[qq * 4 + 1] * inv;
            v.z = e[qq * 4 + 2] * inv;
            v.w = e[qq * 4 + 3] * inv;
            reinterpret_cast<float4*>(out + (size_t)np * GMM_K)[qq] = v;
        }
    }
}

// ---------------------------------------------------------------------------
extern "C" void kernel_launch(void* const* d_in, const int* in_sizes, int n_in,
                              void* d_out, int out_size, void* d_ws, size_t ws_size,
                              hipStream_t stream)
{
    const float* X    = (const float*)d_in[0];
    const float* pi   = (const float*)d_in[1];
    const float* mus  = (const float*)d_in[2];
    const float* covs = (const float*)d_in[3];
    float* out = (float*)d_out;

    const int N = in_sizes[0] / GMM_D;

    _Float16* WA = (_Float16*)d_ws;
    float* tv = (float*)((char*)d_ws + WA_BYTES);
    float* cc = tv + GMM_K * GMM_D;

    gmm_precompute_kernel<<<dim3(GMM_K), dim3(64), 0, stream>>>(pi, mus, covs, WA, tv, cc);

    const int blocks = (N + 63) / 64;  // 200000/64 = 3125 exactly
    gmm_estep_kernel<<<dim3(blocks), dim3(256), 0, stream>>>(X, WA, tv, cc, out, N);
}

// Round 3
// 180.012 us; speedup vs baseline: 4.5642x; 4.5642x over previous
//
#include <hip/hip_runtime.h>
#include <cstddef>
#include <cstdint>

// GMM E-step: N=200000, K=16, D=64, fp32 in/out.
// R8 (resubmit; previous round was a broker infra failure, no counters):
// precompute = single-wave register Cholesky (readlane broadcasts) + LDS
// handoff + register forward-substitution inverse with wave-uniform LDS row
// reads. R7 failed (680us) because A_r[64] and w[64] were live
// simultaneously across a fully-unrolled shuffle-heavy inverse -> VGPR=256 +
// 10.7MB scratch spill traffic. Now at most ONE 64-float array is live at a
// time; phase 2 reads L rows from LDS (uniform broadcast ds_read_b64,
// conflict-free), so the allocator peak is ~75 VGPRs.
// Estep (MFMA f16 hi/lo, verified R5) unchanged.

#define GMM_D 64
#define GMM_K 16

typedef _Float16 half8 __attribute__((ext_vector_type(8)));
typedef float f32x4 __attribute__((ext_vector_type(4)));

// ws: WA [16 comps][16 frags][64 lanes][8 f16] = 262144 B, then tv, cc (f32)
#define WA_BYTES (GMM_K * 16 * 64 * 8 * 2)

__device__ __forceinline__ float fast_rsqrt(float x) {
#if __has_builtin(__builtin_amdgcn_rsqf)
    // v_rsq_f32 (~1 ulp) + one Newton step -> full fp32 accuracy
    const float r = __builtin_amdgcn_rsqf(x);
    return r * (1.5f - 0.5f * x * r * r);
#else
    return 1.0f / sqrtf(x);
#endif
}

// broadcast lane l's value of v to all lanes (l compile-time after unroll)
__device__ __forceinline__ float lane_bcast(float v, int l) {
    return __int_as_float(__builtin_amdgcn_readlane(__float_as_int(v), l));
}

// ---------------------------------------------------------------------------
// Precompute: one WAVE (64 threads) per component, wave-synchronous, no
// multi-wave barriers. Phase 1: lane r owns row r of Sigma in VGPRs ->
// Cholesky via readlane column broadcasts. Dump L to LDS (upper zeroed).
// Phase 2: lane r solves L w = e_r (column r of W=L^{-1}) reading L's rows
// from LDS with wave-uniform float2 loads. All loops fully unrolled so every
// per-lane array index is a compile-time constant (no scratch).
// ---------------------------------------------------------------------------
__global__ __launch_bounds__(64) void gmm_precompute_kernel(
    const float* __restrict__ pi, const float* __restrict__ mus,
    const float* __restrict__ covs, _Float16* __restrict__ WA,
    float* __restrict__ tv, float* __restrict__ cc)
{
    const int k = blockIdx.x;
    const int r = threadIdx.x;  // lane id

    __shared__ float Ls[GMM_D][66];          // L rows, upper tri zeroed; stride 66
                                             // keeps rows 8B-aligned for b64 reads
    __shared__ float Wv[GMM_D][GMM_D + 1];   // W = L^{-1}, for t/swizzle epilogue

    // ---- load row r of Sigma into registers (16x float4, L2-resident) ----
    float A_r[GMM_D];
    {
        const float4* src = reinterpret_cast<const float4*>(
            covs + (size_t)k * GMM_D * GMM_D + (size_t)r * GMM_D);
        #pragma unroll
        for (int u = 0; u < GMM_D / 4; ++u) {
            const float4 v = src[u];
            A_r[4 * u + 0] = v.x; A_r[4 * u + 1] = v.y;
            A_r[4 * u + 2] = v.z; A_r[4 * u + 3] = v.w;
        }
    }

    // ---- Phase 1: register Cholesky, right-looking, zero barriers ----
    // After step j: A_r[j] = L[r][j] (valid for r >= j; lanes r < j hold junk
    // that is never read: every broadcast reads lanes >= j).
    float mydiag = 1.0f, myrs = 1.0f;
    #pragma unroll
    for (int j = 0; j < GMM_D; ++j) {
        const float pivot = lane_bcast(A_r[j], j);   // lane j: valid diag
        const float rs = fast_rsqrt(pivot);
        const float valj = A_r[j] * rs;              // L[r][j]; lane j: sqrt(pivot)
        if (r == j) { mydiag = valj; myrs = rs; }
        A_r[j] = valj;
        #pragma unroll
        for (int p = j + 1; p < GMM_D; ++p)          // rank-1 trailing update
            A_r[p] -= valj * lane_bcast(valj, p);    // L[p][j] from lane p
    }

    // ---- handoff: dump L rows to LDS, upper triangle zeroed.  A_r dies here.
    #pragma unroll
    for (int p = 0; p < GMM_D; ++p)
        Ls[r][p] = (p <= r) ? A_r[p] : 0.0f;
    __syncthreads();   // single wave: cheap

    // ---- Phase 2: lane r solves L w = e_r; only w[64] live in registers ----
    // w pre-zeroed + zeroed upper triangle => vector groups may safely cover
    // p in [2u, 2u+1] up to u = i>>1: junk terms are exactly 0*0.
    float w[GMM_D];
    #pragma unroll
    for (int i = 0; i < GMM_D; ++i) w[i] = 0.0f;

    #pragma unroll
    for (int i = 0; i < GMM_D; ++i) {
        // wave-uniform address -> broadcast ds_read_b64, conflict-free
        const float2* Lrow = reinterpret_cast<const float2*>(&Ls[i][0]);
        float a0 = 0.0f, a1 = 0.0f;
        #pragma unroll
        for (int u = 0; u <= (i >> 1); ++u) {
            const float2 lv = Lrow[u];
            a0 -= lv.x * w[2 * u + 0];
            a1 -= lv.y * w[2 * u + 1];
        }
        const float invd = lane_bcast(myrs, i);      // 1/L[i][i]
        const float dlt = (r == i) ? 1.0f : 0.0f;
        w[i] = (dlt + a0 + a1) * invd;
    }

    // ---- dump W to LDS (lane r holds column r -> write transposed) ----
    #pragma unroll
    for (int i = 0; i < GMM_D; ++i)
        Wv[i][r] = w[i];          // consecutive addresses per instr: conflict-free
    __syncthreads();

    // ---- t = W mu (lane r computes row r; mk[] loads are wave-uniform) ----
    {
        const float* mk = mus + k * GMM_D;
        float s0 = 0.f, s1 = 0.f, s2 = 0.f, s3 = 0.f;
        #pragma unroll
        for (int c = 0; c < GMM_D; c += 4) {
            s0 += Wv[r][c + 0] * mk[c + 0];
            s1 += Wv[r][c + 1] * mk[c + 1];
            s2 += Wv[r][c + 2] * mk[c + 2];
            s3 += Wv[r][c + 3] * mk[c + 3];
        }
        tv[k * GMM_D + r] = (s0 + s1) + (s2 + s3);
    }

    // ---- swizzle W -> f16 hi/lo A-fragments (layout identical to R6) ----
    // frag f = mt*4+s: lane L elem u = W[mt*16 + (L&15)][(s&1)*32 + (L>>4)*8 + u],
    // s in {0,1}: hi ; {2,3}: lo. 16B/lane stores, coalesced.
    {
        const int lr = r & 15, q = r >> 4;
        #pragma unroll
        for (int f = 0; f < 16; ++f) {
            const int mt = f >> 2, s = f & 3;
            const int row = mt * 16 + lr;
            const int db = (s & 1) * 32 + q * 8;
            half8 hv;
            #pragma unroll
            for (int u = 0; u < 8; ++u) {
                const float v = Wv[row][db + u];
                _Float16 h = (_Float16)v;
                if (s >= 2) h = (_Float16)(v - (float)h);
                hv[u] = h;
            }
            *(half8*)(WA + ((size_t)((k * 16 + f) * 64) + r) * 8) = hv;
        }
    }

    // ---- c_k = log pi_k - sum(log L_ii) - 0.5*D*log(2*pi) ----
    {
        float ll = logf(mydiag);
        #pragma unroll
        for (int off = 32; off > 0; off >>= 1) ll += __shfl_down(ll, off);
        if (r == 0)
            cc[k] = logf(pi[k]) - ll - 0.5f * 64.0f * 1.8378770664093453f;
    }
}

// ---------------------------------------------------------------------------
// E-step (R5-verified, unchanged): block = 4 waves, 64 points; wave w owns
// comps 4w..4w+3. Per (comp, ntile): 4 Mtiles x 6 MFMA 16x16x32 f16 (hi*hi +
// hi*lo + lo*hi), C preloaded with -t, maha reduced in-register + 2 shfl_xor.
// ---------------------------------------------------------------------------
__global__ __launch_bounds__(256) void gmm_estep_kernel(
    const float* __restrict__ X, const _Float16* __restrict__ WA,
    const float* __restrict__ tv, const float* __restrict__ cc,
    float* __restrict__ out, int N)
{
    // xs row (per point): [hi 0..63 | lo 0..63 | pad 8] f16 = 136 (272 B)
    __shared__ _Float16 xs[64 * 136];
    __shared__ float lg[64 * 17];

    const int tid = threadIdx.x;

    // ---- stage X -> f16 hi/lo in LDS: thread t: point t/4, dims (t%4)*16.. ----
    {
        const int p = tid >> 2, qq = tid & 3;
        const int np = blockIdx.x * 64 + p;
        if (np < N) {
            const float4* src = reinterpret_cast<const float4*>(X + (size_t)np * GMM_D) + qq * 4;
            float vv[16];
            #pragma unroll
            for (int u = 0; u < 4; ++u) {
                const float4 v = src[u];
                vv[4 * u + 0] = v.x; vv[4 * u + 1] = v.y;
                vv[4 * u + 2] = v.z; vv[4 * u + 3] = v.w;
            }
            half8 h0, h1, l0, l1;
            #pragma unroll
            for (int u = 0; u < 8; ++u) {
                const _Float16 a = (_Float16)vv[u];
                const _Float16 b = (_Float16)vv[u + 8];
                h0[u] = a; l0[u] = (_Float16)(vv[u] - (float)a);
                h1[u] = b; l1[u] = (_Float16)(vv[u + 8] - (float)b);
            }
            _Float16* row = xs + p * 136;
            *(half8*)(row + qq * 16)          = h0;
            *(half8*)(row + qq * 16 + 8)      = h1;
            *(half8*)(row + 64 + qq * 16)     = l0;
            *(half8*)(row + 64 + qq * 16 + 8) = l1;
        }
    }
    __syncthreads();

    const int lane = tid & 63;
    const int wave = __builtin_amdgcn_readfirstlane(tid >> 6);
    const int pt = lane & 15;
    const int q  = lane >> 4;

    #pragma unroll 1
    for (int kk = 0; kk < 4; ++kk) {
        const int k = wave * 4 + kk;  // wave-uniform

        // A fragments: 16 x global_load_dwordx4, coalesced, L2-resident.
        half8 af[4][4];
        const _Float16* wab = WA + (size_t)k * 8192 + lane * 8;
        #pragma unroll
        for (int mt = 0; mt < 4; ++mt)
            #pragma unroll
            for (int s = 0; s < 4; ++s)
                af[mt][s] = *(const half8*)(wab + (mt * 4 + s) * 512);

        // nt-invariant accumulator inits: -t rows for each Mtile
        f32x4 tk4[4];
        #pragma unroll
        for (int mt = 0; mt < 4; ++mt)
            tk4[mt] = *(const f32x4*)(tv + k * 64 + mt * 16 + q * 4);

        #pragma unroll 1
        for (int nt = 0; nt < 4; ++nt) {
            const _Float16* xrow = xs + (nt * 16 + pt) * 136 + q * 8;
            const half8 bh0 = *(const half8*)(xrow);        // hi dims 0..31
            const half8 bh1 = *(const half8*)(xrow + 32);   // hi dims 32..63
            const half8 bl0 = *(const half8*)(xrow + 64);   // lo dims 0..31
            const half8 bl1 = *(const half8*)(xrow + 96);   // lo dims 32..63

            float mahaP = 0.0f;
            #pragma unroll
            for (int mt = 0; mt < 4; ++mt) {
                f32x4 c = -tk4[mt];
                c = __builtin_amdgcn_mfma_f32_16x16x32_f16(af[mt][0], bh0, c, 0, 0, 0);
                c = __builtin_amdgcn_mfma_f32_16x16x32_f16(af[mt][1], bh1, c, 0, 0, 0);
                c = __builtin_amdgcn_mfma_f32_16x16x32_f16(af[mt][0], bl0, c, 0, 0, 0);
                c = __builtin_amdgcn_mfma_f32_16x16x32_f16(af[mt][1], bl1, c, 0, 0, 0);
                c = __builtin_amdgcn_mfma_f32_16x16x32_f16(af[mt][2], bh0, c, 0, 0, 0);
                c = __builtin_amdgcn_mfma_f32_16x16x32_f16(af[mt][3], bh1, c, 0, 0, 0);
                mahaP += c[0] * c[0] + c[1] * c[1] + c[2] * c[2] + c[3] * c[3];
            }
            mahaP += __shfl_xor(mahaP, 16);
            mahaP += __shfl_xor(mahaP, 32);
            if (q == 0 && (blockIdx.x * 64 + nt * 16 + pt) < N)
                lg[(nt * 16 + pt) * 17 + k] = cc[k] - 0.5f * mahaP;
        }
    }
    __syncthreads();

    // softmax: 4 threads/point, one float4 each (contiguous stores)
    {
        const int p = tid >> 2, qq = tid & 3;
        const int np = blockIdx.x * 64 + p;
        if (np < N) {
            const float* row = &lg[p * 17];
            float m = row[0];
            #pragma unroll
            for (int j = 1; j < GMM_K; ++j) m = fmaxf(m, row[j]);
            float e[GMM_K];
            float s = 0.0f;
            #pragma unroll
            for (int j = 0; j < GMM_K; ++j) { e[j] = __expf(row[j] - m); s += e[j]; }
            const float inv = 1.0f / s;
            float4 v;
            v.x = e[qq * 4 + 0] * inv;
            v.y = e[qq * 4 + 1] * inv;
            v.z = e[qq * 4 + 2] * inv;
            v.w = e[qq * 4 + 3] * inv;
            reinterpret_cast<float4*>(out + (size_t)np * GMM_K)[qq] = v;
        }
    }
}

// ---------------------------------------------------------------------------
extern "C" void kernel_launch(void* const* d_in, const int* in_sizes, int n_in,
                              void* d_out, int out_size, void* d_ws, size_t ws_size,
                              hipStream_t stream)
{
    const float* X    = (const float*)d_in[0];
    const float* pi   = (const float*)d_in[1];
    const float* mus  = (const float*)d_in[2];
    const float* covs = (const float*)d_in[3];
    float* out = (float*)d_out;

    const int N = in_sizes[0] / GMM_D;

    _Float16* WA = (_Float16*)d_ws;
    float* tv = (float*)((char*)d_ws + WA_BYTES);
    float* cc = tv + GMM_K * GMM_D;

    gmm_precompute_kernel<<<dim3(GMM_K), dim3(64), 0, stream>>>(pi, mus, covs, WA, tv, cc);

    const int blocks = (N + 63) / 64;  // 200000/64 = 3125 exactly
    gmm_estep_kernel<<<dim3(blocks), dim3(256), 0, stream>>>(X, WA, tv, cc, out, N);
}

// Round 4
// 176.028 us; speedup vs baseline: 4.6675x; 1.0226x over previous
//
#include <hip/hip_runtime.h>
#include <cstddef>
#include <cstdint>

// GMM E-step: N=200000, K=16, D=64, fp32 in/out.
// R9: (a) tv now stores NEGATED t = -(W mu): estep's accumulator init
// becomes c = tk4 directly, deleting 256 f32 negates/wave (~30% of estep
// VALU; estep measured MfmaUtil 45% + VALUBusy 45% = sum-bound, so VALU
// instruction count is the lever). (b) precompute phase-2 reads L rows via
// ds_read_b128 (Ls stride 68, 16B-aligned rows, 4-way accumulators): 544
// b128 instead of 1056 b64 uniform reads on the 16-CU serial path.
// Structure otherwise identical to R8 (verified: single-wave register
// Cholesky + LDS handoff + register forward-substitution inverse).

#define GMM_D 64
#define GMM_K 16

typedef _Float16 half8 __attribute__((ext_vector_type(8)));
typedef float f32x4 __attribute__((ext_vector_type(4)));

// ws: WA [16 comps][16 frags][64 lanes][8 f16] = 262144 B, then tv, cc (f32)
#define WA_BYTES (GMM_K * 16 * 64 * 8 * 2)

__device__ __forceinline__ float fast_rsqrt(float x) {
#if __has_builtin(__builtin_amdgcn_rsqf)
    // v_rsq_f32 (~1 ulp) + one Newton step -> full fp32 accuracy
    const float r = __builtin_amdgcn_rsqf(x);
    return r * (1.5f - 0.5f * x * r * r);
#else
    return 1.0f / sqrtf(x);
#endif
}

// broadcast lane l's value of v to all lanes (l compile-time after unroll)
__device__ __forceinline__ float lane_bcast(float v, int l) {
    return __int_as_float(__builtin_amdgcn_readlane(__float_as_int(v), l));
}

// ---------------------------------------------------------------------------
// Precompute: one WAVE (64 threads) per component, wave-synchronous, no
// multi-wave barriers. Phase 1: lane r owns row r of Sigma in VGPRs ->
// Cholesky via readlane column broadcasts. Dump L to LDS (upper zeroed).
// Phase 2: lane r solves L w = e_r (column r of W=L^{-1}) reading L's rows
// with wave-uniform b128 loads. All loops fully unrolled so every per-lane
// array index is a compile-time constant (no scratch). At most one 64-float
// register array live at a time (R7 lesson: two live arrays -> 256 VGPR +
// scratch spills -> 680us).
// ---------------------------------------------------------------------------
__global__ __launch_bounds__(64) void gmm_precompute_kernel(
    const float* __restrict__ pi, const float* __restrict__ mus,
    const float* __restrict__ covs, _Float16* __restrict__ WA,
    float* __restrict__ tv, float* __restrict__ cc)
{
    const int k = blockIdx.x;
    const int r = threadIdx.x;  // lane id

    __shared__ alignas(16) float Ls[GMM_D][68];  // L rows, upper tri zeroed;
                                                 // stride 68 floats = 272 B
                                                 // -> rows 16B-aligned (b128)
    __shared__ float Wv[GMM_D][GMM_D + 1];       // W = L^{-1}, for epilogue

    // ---- load row r of Sigma into registers (16x float4, L2-resident) ----
    float A_r[GMM_D];
    {
        const float4* src = reinterpret_cast<const float4*>(
            covs + (size_t)k * GMM_D * GMM_D + (size_t)r * GMM_D);
        #pragma unroll
        for (int u = 0; u < GMM_D / 4; ++u) {
            const float4 v = src[u];
            A_r[4 * u + 0] = v.x; A_r[4 * u + 1] = v.y;
            A_r[4 * u + 2] = v.z; A_r[4 * u + 3] = v.w;
        }
    }

    // ---- Phase 1: register Cholesky, right-looking, zero barriers ----
    // After step j: A_r[j] = L[r][j] (valid for r >= j; lanes r < j hold junk
    // that is never read: every broadcast reads lanes >= j). Verified R8.
    float mydiag = 1.0f, myrs = 1.0f;
    #pragma unroll
    for (int j = 0; j < GMM_D; ++j) {
        const float pivot = lane_bcast(A_r[j], j);   // lane j: valid diag
        const float rs = fast_rsqrt(pivot);
        const float valj = A_r[j] * rs;              // L[r][j]; lane j: sqrt(pivot)
        if (r == j) { mydiag = valj; myrs = rs; }
        A_r[j] = valj;
        #pragma unroll
        for (int p = j + 1; p < GMM_D; ++p)          // rank-1 trailing update
            A_r[p] -= valj * lane_bcast(valj, p);    // L[p][j] from lane p
    }

    // ---- handoff: dump L rows to LDS, upper triangle zeroed.  A_r dies here.
    #pragma unroll
    for (int p = 0; p < GMM_D; ++p)
        Ls[r][p] = (p <= r) ? A_r[p] : 0.0f;
    __syncthreads();   // single wave: cheap

    // ---- Phase 2: lane r solves L w = e_r; only w[64] live in registers ----
    // w pre-zeroed + zeroed upper triangle => b128 groups may safely cover
    // p in [4u, 4u+3] up to u = i>>2 (max p = 63): junk terms are exactly 0*0.
    float w[GMM_D];
    #pragma unroll
    for (int i = 0; i < GMM_D; ++i) w[i] = 0.0f;

    #pragma unroll
    for (int i = 0; i < GMM_D; ++i) {
        // wave-uniform address -> broadcast ds_read_b128, conflict-free
        const f32x4* Lrow = reinterpret_cast<const f32x4*>(&Ls[i][0]);
        float a0 = 0.0f, a1 = 0.0f, a2 = 0.0f, a3 = 0.0f;
        #pragma unroll
        for (int u = 0; u <= (i >> 2); ++u) {
            const f32x4 lv = Lrow[u];
            a0 -= lv[0] * w[4 * u + 0];
            a1 -= lv[1] * w[4 * u + 1];
            a2 -= lv[2] * w[4 * u + 2];
            a3 -= lv[3] * w[4 * u + 3];
        }
        const float invd = lane_bcast(myrs, i);      // 1/L[i][i]
        const float dlt = (r == i) ? 1.0f : 0.0f;
        w[i] = (dlt + (a0 + a1) + (a2 + a3)) * invd;
    }

    // ---- dump W to LDS (lane r holds column r -> write transposed) ----
    #pragma unroll
    for (int i = 0; i < GMM_D; ++i)
        Wv[i][r] = w[i];          // consecutive addresses per instr: conflict-free
    __syncthreads();

    // ---- tv = -(W mu): NEGATED so estep's MFMA C-init needs no negate ----
    {
        const float* mk = mus + k * GMM_D;
        float s0 = 0.f, s1 = 0.f, s2 = 0.f, s3 = 0.f;
        #pragma unroll
        for (int c = 0; c < GMM_D; c += 4) {
            s0 += Wv[r][c + 0] * mk[c + 0];
            s1 += Wv[r][c + 1] * mk[c + 1];
            s2 += Wv[r][c + 2] * mk[c + 2];
            s3 += Wv[r][c + 3] * mk[c + 3];
        }
        tv[k * GMM_D + r] = -((s0 + s1) + (s2 + s3));
    }

    // ---- swizzle W -> f16 hi/lo A-fragments (layout identical to R6) ----
    // frag f = mt*4+s: lane L elem u = W[mt*16 + (L&15)][(s&1)*32 + (L>>4)*8 + u],
    // s in {0,1}: hi ; {2,3}: lo. 16B/lane stores, coalesced.
    {
        const int lr = r & 15, q = r >> 4;
        #pragma unroll
        for (int f = 0; f < 16; ++f) {
            const int mt = f >> 2, s = f & 3;
            const int row = mt * 16 + lr;
            const int db = (s & 1) * 32 + q * 8;
            half8 hv;
            #pragma unroll
            for (int u = 0; u < 8; ++u) {
                const float v = Wv[row][db + u];
                _Float16 h = (_Float16)v;
                if (s >= 2) h = (_Float16)(v - (float)h);
                hv[u] = h;
            }
            *(half8*)(WA + ((size_t)((k * 16 + f) * 64) + r) * 8) = hv;
        }
    }

    // ---- c_k = log pi_k - sum(log L_ii) - 0.5*D*log(2*pi) ----
    {
        float ll = logf(mydiag);
        #pragma unroll
        for (int off = 32; off > 0; off >>= 1) ll += __shfl_down(ll, off);
        if (r == 0)
            cc[k] = logf(pi[k]) - ll - 0.5f * 64.0f * 1.8378770664093453f;
    }
}

// ---------------------------------------------------------------------------
// E-step: block = 4 waves, 64 points; wave w owns comps 4w..4w+3.
// Per (comp, ntile): 4 Mtiles x 6 MFMA 16x16x32 f16 (hi*hi + hi*lo + lo*hi),
// C preloaded with -t (tv already negated), maha reduced in-register +
// 2 shfl_xor. Numerics identical to R5-verified version.
// ---------------------------------------------------------------------------
__global__ __launch_bounds__(256) void gmm_estep_kernel(
    const float* __restrict__ X, const _Float16* __restrict__ WA,
    const float* __restrict__ tv, const float* __restrict__ cc,
    float* __restrict__ out, int N)
{
    // xs row (per point): [hi 0..63 | lo 0..63 | pad 8] f16 = 136 (272 B)
    __shared__ _Float16 xs[64 * 136];
    __shared__ float lg[64 * 17];

    const int tid = threadIdx.x;

    // ---- stage X -> f16 hi/lo in LDS: thread t: point t/4, dims (t%4)*16.. ----
    {
        const int p = tid >> 2, qq = tid & 3;
        const int np = blockIdx.x * 64 + p;
        if (np < N) {
            const float4* src = reinterpret_cast<const float4*>(X + (size_t)np * GMM_D) + qq * 4;
            float vv[16];
            #pragma unroll
            for (int u = 0; u < 4; ++u) {
                const float4 v = src[u];
                vv[4 * u + 0] = v.x; vv[4 * u + 1] = v.y;
                vv[4 * u + 2] = v.z; vv[4 * u + 3] = v.w;
            }
            half8 h0, h1, l0, l1;
            #pragma unroll
            for (int u = 0; u < 8; ++u) {
                const _Float16 a = (_Float16)vv[u];
                const _Float16 b = (_Float16)vv[u + 8];
                h0[u] = a; l0[u] = (_Float16)(vv[u] - (float)a);
                h1[u] = b; l1[u] = (_Float16)(vv[u + 8] - (float)b);
            }
            _Float16* row = xs + p * 136;
            *(half8*)(row + qq * 16)          = h0;
            *(half8*)(row + qq * 16 + 8)      = h1;
            *(half8*)(row + 64 + qq * 16)     = l0;
            *(half8*)(row + 64 + qq * 16 + 8) = l1;
        }
    }
    __syncthreads();

    const int lane = tid & 63;
    const int wave = __builtin_amdgcn_readfirstlane(tid >> 6);
    const int pt = lane & 15;
    const int q  = lane >> 4;

    #pragma unroll 1
    for (int kk = 0; kk < 4; ++kk) {
        const int k = wave * 4 + kk;  // wave-uniform

        // A fragments: 16 x global_load_dwordx4, coalesced, L2-resident.
        half8 af[4][4];
        const _Float16* wab = WA + (size_t)k * 8192 + lane * 8;
        #pragma unroll
        for (int mt = 0; mt < 4; ++mt)
            #pragma unroll
            for (int s = 0; s < 4; ++s)
                af[mt][s] = *(const half8*)(wab + (mt * 4 + s) * 512);

        // nt-invariant accumulator inits: tv holds -t, so no negate needed
        f32x4 tk4[4];
        #pragma unroll
        for (int mt = 0; mt < 4; ++mt)
            tk4[mt] = *(const f32x4*)(tv + k * 64 + mt * 16 + q * 4);

        #pragma unroll 1
        for (int nt = 0; nt < 4; ++nt) {
            const _Float16* xrow = xs + (nt * 16 + pt) * 136 + q * 8;
            const half8 bh0 = *(const half8*)(xrow);        // hi dims 0..31
            const half8 bh1 = *(const half8*)(xrow + 32);   // hi dims 32..63
            const half8 bl0 = *(const half8*)(xrow + 64);   // lo dims 0..31
            const half8 bl1 = *(const half8*)(xrow + 96);   // lo dims 32..63

            float mahaP = 0.0f;
            #pragma unroll
            for (int mt = 0; mt < 4; ++mt) {
                f32x4 c = tk4[mt];   // = -t (pre-negated in precompute)
                c = __builtin_amdgcn_mfma_f32_16x16x32_f16(af[mt][0], bh0, c, 0, 0, 0);
                c = __builtin_amdgcn_mfma_f32_16x16x32_f16(af[mt][1], bh1, c, 0, 0, 0);
                c = __builtin_amdgcn_mfma_f32_16x16x32_f16(af[mt][0], bl0, c, 0, 0, 0);
                c = __builtin_amdgcn_mfma_f32_16x16x32_f16(af[mt][1], bl1, c, 0, 0, 0);
                c = __builtin_amdgcn_mfma_f32_16x16x32_f16(af[mt][2], bh0, c, 0, 0, 0);
                c = __builtin_amdgcn_mfma_f32_16x16x32_f16(af[mt][3], bh1, c, 0, 0, 0);
                mahaP += c[0] * c[0] + c[1] * c[1] + c[2] * c[2] + c[3] * c[3];
            }
            mahaP += __shfl_xor(mahaP, 16);
            mahaP += __shfl_xor(mahaP, 32);
            if (q == 0 && (blockIdx.x * 64 + nt * 16 + pt) < N)
                lg[(nt * 16 + pt) * 17 + k] = cc[k] - 0.5f * mahaP;
        }
    }
    __syncthreads();

    // softmax: 4 threads/point, one float4 each (contiguous stores)
    {
        const int p = tid >> 2, qq = tid & 3;
        const int np = blockIdx.x * 64 + p;
        if (np < N) {
            const float* row = &lg[p * 17];
            float m = row[0];
            #pragma unroll
            for (int j = 1; j < GMM_K; ++j) m = fmaxf(m, row[j]);
            float e[GMM_K];
            float s = 0.0f;
            #pragma unroll
            for (int j = 0; j < GMM_K; ++j) { e[j] = __expf(row[j] - m); s += e[j]; }
            const float inv = 1.0f / s;
            float4 v;
            v.x = e[qq * 4 + 0] * inv;
            v.y = e[qq * 4 + 1] * inv;
            v.z = e[qq * 4 + 2] * inv;
            v.w = e[qq * 4 + 3] * inv;
            reinterpret_cast<float4*>(out + (size_t)np * GMM_K)[qq] = v;
        }
    }
}

// ---------------------------------------------------------------------------
extern "C" void kernel_launch(void* const* d_in, const int* in_sizes, int n_in,
                              void* d_out, int out_size, void* d_ws, size_t ws_size,
                              hipStream_t stream)
{
    const float* X    = (const float*)d_in[0];
    const float* pi   = (const float*)d_in[1];
    const float* mus  = (const float*)d_in[2];
    const float* covs = (const float*)d_in[3];
    float* out = (float*)d_out;

    const int N = in_sizes[0] / GMM_D;

    _Float16* WA = (_Float16*)d_ws;
    float* tv = (float*)((char*)d_ws + WA_BYTES);
    float* cc = tv + GMM_K * GMM_D;

    gmm_precompute_kernel<<<dim3(GMM_K), dim3(64), 0, stream>>>(pi, mus, covs, WA, tv, cc);

    const int blocks = (N + 63) / 64;  // 200000/64 = 3125 exactly
    gmm_estep_kernel<<<dim3(blocks), dim3(256), 0, stream>>>(X, WA, tv, cc, out, N);
}